// Round 3
// baseline (579.270 us; speedup 1.0000x reference)
//
#include <hip/hip_runtime.h>

#define D_MODEL 1024
#define NHEADS  16
#define DKH     64
#define BSZ     2
#define TLEN    2048
#define MTOT    (BSZ*TLEN)   // 4096

typedef unsigned short u16;
typedef unsigned int   u32;
typedef unsigned char  u8;
typedef __attribute__((ext_vector_type(8))) short short8;
typedef __attribute__((ext_vector_type(4))) float floatx4;

// ---------------- fp32 -> (bf16 hi, bf16 lo) split helpers ----------------
__device__ __forceinline__ u16 f2bf(float x) {
    u32 u = __float_as_uint(x);
    u += 0x7FFFu + ((u >> 16) & 1u);   // RNE
    return (u16)(u >> 16);
}
__device__ __forceinline__ float bf2f(u16 h) { return __uint_as_float(((u32)h) << 16); }

__global__ __launch_bounds__(256) void split_bf16x2(
    const float* __restrict__ in, u16* __restrict__ hi, u16* __restrict__ lo)
{
    const int idx = (blockIdx.x * 256 + threadIdx.x) * 4;
    float4 v = *(const float4*)&in[idx];
    u16 h0 = f2bf(v.x), h1 = f2bf(v.y), h2 = f2bf(v.z), h3 = f2bf(v.w);
    u16 l0 = f2bf(v.x - bf2f(h0));
    u16 l1 = f2bf(v.y - bf2f(h1));
    u16 l2 = f2bf(v.z - bf2f(h2));
    u16 l3 = f2bf(v.w - bf2f(h3));
    uint2 hv, lv;
    hv.x = (u32)h0 | ((u32)h1 << 16);  hv.y = (u32)h2 | ((u32)h3 << 16);
    lv.x = (u32)l0 | ((u32)l1 << 16);  lv.y = (u32)l2 | ((u32)l3 << 16);
    *(uint2*)&hi[idx] = hv;
    *(uint2*)&lo[idx] = lv;
}

// ---------------- V transpose + split: Vb[4096][1024] fp32 -> Vt[bh][64 d][2048 t] bf16 hi/lo ----------------
__global__ __launch_bounds__(256) void vsplit_t(
    const float* __restrict__ V, u16* __restrict__ Vth, u16* __restrict__ Vtl)
{
    __shared__ float Vs[64][68];
    const int tid = threadIdx.x;
    const int t0  = blockIdx.x * 64;
    const int bh  = blockIdx.y;
    const int b   = bh >> 4, h = bh & 15;
    const size_t inbase = ((size_t)b * TLEN + t0) * D_MODEL + h * DKH;

    #pragma unroll
    for (int it = 0; it < 4; ++it) {
        int i = tid + it * 256;
        int r = i >> 4, cq = i & 15;
        *(float4*)&Vs[r][4*cq] = *(const float4*)&V[inbase + (size_t)r * D_MODEL + 4*cq];
    }
    __syncthreads();

    const size_t outbase = (size_t)bh * DKH * TLEN + t0;
    #pragma unroll
    for (int it = 0; it < 4; ++it) {
        int i = tid + it * 256;
        int d = i >> 4, ck = i & 15;
        int tk = 4 * ck;
        float v0 = Vs[tk+0][d], v1 = Vs[tk+1][d], v2 = Vs[tk+2][d], v3 = Vs[tk+3][d];
        u16 h0 = f2bf(v0), h1 = f2bf(v1), h2 = f2bf(v2), h3 = f2bf(v3);
        u16 l0 = f2bf(v0 - bf2f(h0));
        u16 l1 = f2bf(v1 - bf2f(h1));
        u16 l2 = f2bf(v2 - bf2f(h2));
        u16 l3 = f2bf(v3 - bf2f(h3));
        uint2 hv, lv;
        hv.x = (u32)h0 | ((u32)h1 << 16);  hv.y = (u32)h2 | ((u32)h3 << 16);
        lv.x = (u32)l0 | ((u32)l1 << 16);  lv.y = (u32)l2 | ((u32)l3 << 16);
        *(uint2*)&Vth[outbase + (size_t)d * TLEN + tk] = hv;
        *(uint2*)&Vtl[outbase + (size_t)d * TLEN + tk] = lv;
    }
}

// ---------------- bf16x3 MFMA GEMM: C[m][n] = sum_k A[m][k]*W[n][k], K=N=1024 ----------------
// 128x128 tile, BK=32, 4 waves (2x2), each wave 64x64 = 4x4 frags of 16x16x32.
// LDS fragment-major: chunk c (16B) = sub-tile (c>>6), lane (c&63); lane l of sub-tile s
// holds row s*16+(l&15), k = (l>>4)*8..+7 -> ds_reads lane-linear, conflict-free.
__global__ __launch_bounds__(256) void gemm_bf16x3(
    const u16* __restrict__ Ahi, const u16* __restrict__ Alo,
    const u16* __restrict__ B0h, const u16* __restrict__ B0l,
    const u16* __restrict__ B1h, const u16* __restrict__ B1l,
    const u16* __restrict__ B2h, const u16* __restrict__ B2l,
    float* __restrict__ C0, float* __restrict__ C1, float* __restrict__ C2)
{
    const u16* __restrict__ Bh = (blockIdx.z == 0) ? B0h : ((blockIdx.z == 1) ? B1h : B2h);
    const u16* __restrict__ Bl = (blockIdx.z == 0) ? B0l : ((blockIdx.z == 1) ? B1l : B2l);
    float* __restrict__ C      = (blockIdx.z == 0) ? C0  : ((blockIdx.z == 1) ? C1  : C2);

    __shared__ __align__(16) short lds[4][4096];   // Ahi, Alo, Bhi, Blo tiles

    const int tid  = threadIdx.x;
    const int lane = tid & 63;
    const int w    = tid >> 6;
    const int wr   = w >> 1;
    const int wc   = w & 1;
    const int m0   = blockIdx.y * 128;
    const int n0   = blockIdx.x * 128;
    const int lr   = lane & 15;
    const int lkq  = lane >> 4;

    const size_t offA0 = (size_t)(m0 + (w*2 + 0)*16 + lr) * D_MODEL + lkq*8;
    const size_t offA1 = (size_t)(m0 + (w*2 + 1)*16 + lr) * D_MODEL + lkq*8;
    const size_t offB0 = (size_t)(n0 + (w*2 + 0)*16 + lr) * D_MODEL + lkq*8;
    const size_t offB1 = (size_t)(n0 + (w*2 + 1)*16 + lr) * D_MODEL + lkq*8;

    floatx4 acc[4][4];
    #pragma unroll
    for (int i = 0; i < 4; ++i)
        #pragma unroll
        for (int j = 0; j < 4; ++j) acc[i][j] = (floatx4){0.f, 0.f, 0.f, 0.f};

    short8 sA0h, sA1h, sA0l, sA1l, sB0h, sB1h, sB0l, sB1l;
    sA0h = *(const short8*)(Ahi + offA0);  sA1h = *(const short8*)(Ahi + offA1);
    sA0l = *(const short8*)(Alo + offA0);  sA1l = *(const short8*)(Alo + offA1);
    sB0h = *(const short8*)(Bh  + offB0);  sB1h = *(const short8*)(Bh  + offB1);
    sB0l = *(const short8*)(Bl  + offB0);  sB1l = *(const short8*)(Bl  + offB1);

    const int c0 = (w*128 + 0*64 + lane) * 8;
    const int c1 = (w*128 + 1*64 + lane) * 8;

    for (int ks = 0; ks < D_MODEL/32; ++ks) {
        *(short8*)&lds[0][c0] = sA0h;  *(short8*)&lds[0][c1] = sA1h;
        *(short8*)&lds[1][c0] = sA0l;  *(short8*)&lds[1][c1] = sA1l;
        *(short8*)&lds[2][c0] = sB0h;  *(short8*)&lds[2][c1] = sB1h;
        *(short8*)&lds[3][c0] = sB0l;  *(short8*)&lds[3][c1] = sB1l;
        __syncthreads();

        if (ks + 1 < D_MODEL/32) {
            const size_t kb = (size_t)(ks + 1) * 32;
            sA0h = *(const short8*)(Ahi + offA0 + kb);  sA1h = *(const short8*)(Ahi + offA1 + kb);
            sA0l = *(const short8*)(Alo + offA0 + kb);  sA1l = *(const short8*)(Alo + offA1 + kb);
            sB0h = *(const short8*)(Bh  + offB0 + kb);  sB1h = *(const short8*)(Bh  + offB1 + kb);
            sB0l = *(const short8*)(Bl  + offB0 + kb);  sB1l = *(const short8*)(Bl  + offB1 + kb);
        }

        short8 ah[4], al[4], bh[4], bl[4];
        #pragma unroll
        for (int i = 0; i < 4; ++i) {
            const int ci = ((wr*4 + i)*64 + lane) * 8;
            ah[i] = *(const short8*)&lds[0][ci];
            al[i] = *(const short8*)&lds[1][ci];
        }
        #pragma unroll
        for (int j = 0; j < 4; ++j) {
            const int cj = ((wc*4 + j)*64 + lane) * 8;
            bh[j] = *(const short8*)&lds[2][cj];
            bl[j] = *(const short8*)&lds[3][cj];
        }

        #pragma unroll
        for (int i = 0; i < 4; ++i)
            #pragma unroll
            for (int j = 0; j < 4; ++j) {
                acc[i][j] = __builtin_amdgcn_mfma_f32_16x16x32_bf16(ah[i], bh[j], acc[i][j], 0, 0, 0);
                acc[i][j] = __builtin_amdgcn_mfma_f32_16x16x32_bf16(ah[i], bl[j], acc[i][j], 0, 0, 0);
                acc[i][j] = __builtin_amdgcn_mfma_f32_16x16x32_bf16(al[i], bh[j], acc[i][j], 0, 0, 0);
            }
        __syncthreads();
    }

    // C/D layout: col = lane&15, row = (lane>>4)*4 + reg
    #pragma unroll
    for (int i = 0; i < 4; ++i) {
        const int row0 = m0 + wr*64 + i*16 + (lane >> 4)*4;
        #pragma unroll
        for (int j = 0; j < 4; ++j) {
            const int col = n0 + wc*64 + j*16 + (lane & 15);
            #pragma unroll
            for (int r = 0; r < 4; ++r)
                C[(size_t)(row0 + r) * D_MODEL + col] = acc[i][j][r];
        }
    }
}

// ---------------- MFMA flash attention (bf16x3), causal ----------------
// 4 independent waves per block, 32 q-rows each; K-tiles of 64; K/V frags direct from
// global (L1/L2-shared); P re-split via per-wave LDS (in-order per-wave LDS, no barriers).
__global__ __launch_bounds__(256) void attn_mfma(
    const u16* __restrict__ Qh, const u16* __restrict__ Ql,
    const u16* __restrict__ Kh, const u16* __restrict__ Kl,
    const u16* __restrict__ Vth, const u16* __restrict__ Vtl,
    u16* __restrict__ Ahh, u16* __restrict__ Ahl)
{
    __shared__ __align__(16) float Plds[4][32*68];

    const int tid  = threadIdx.x;
    const int lane = tid & 63;
    const int w    = tid >> 6;
    const int bh   = blockIdx.y;
    const int b    = bh >> 4;
    const int q0   = blockIdx.x * 128 + w * 32;   // this wave's first q row
    const size_t rbase = (size_t)b * TLEN;
    const int hc   = (bh & 15) * DKH;
    const int lr   = lane & 15;
    const int lk   = lane >> 4;

    float* P = Plds[w];

    // Q fragments, held in registers for the whole kernel
    short8 qfh[2][2], qfl[2][2];
    #pragma unroll
    for (int i = 0; i < 2; ++i)
        #pragma unroll
        for (int ks = 0; ks < 2; ++ks) {
            const size_t a = (rbase + q0 + 16*i + lr) * D_MODEL + hc + 32*ks + 8*lk;
            qfh[i][ks] = *(const short8*)(Qh + a);
            qfl[i][ks] = *(const short8*)(Ql + a);
        }

    floatx4 o[2][4];
    float mrun[2][4], lrun[2][4];
    #pragma unroll
    for (int i = 0; i < 2; ++i)
        #pragma unroll
        for (int r = 0; r < 4; ++r) {
            mrun[i][r] = -1e30f; lrun[i][r] = 0.f;
            #pragma unroll
            for (int n = 0; n < 4; ++n) o[i][n][r] = 0.f;
        }

    const int nt = (q0 + 95) >> 6;   // ceil((q0+32)/64) causal tiles for this wave
    for (int kt = 0; kt < nt; ++kt) {
        const int k0 = kt * 64;

        // ---- S = Q K^T (bf16x3) ----
        floatx4 s[2][4];
        #pragma unroll
        for (int i = 0; i < 2; ++i)
            #pragma unroll
            for (int j = 0; j < 4; ++j) s[i][j] = (floatx4){0.f, 0.f, 0.f, 0.f};

        #pragma unroll
        for (int ks = 0; ks < 2; ++ks) {
            short8 kfh[4], kfl[4];
            #pragma unroll
            for (int j = 0; j < 4; ++j) {
                const size_t a = (rbase + k0 + 16*j + lr) * D_MODEL + hc + 32*ks + 8*lk;
                kfh[j] = *(const short8*)(Kh + a);
                kfl[j] = *(const short8*)(Kl + a);
            }
            #pragma unroll
            for (int i = 0; i < 2; ++i)
                #pragma unroll
                for (int j = 0; j < 4; ++j) {
                    s[i][j] = __builtin_amdgcn_mfma_f32_16x16x32_bf16(qfh[i][ks], kfh[j], s[i][j], 0, 0, 0);
                    s[i][j] = __builtin_amdgcn_mfma_f32_16x16x32_bf16(qfh[i][ks], kfl[j], s[i][j], 0, 0, 0);
                    s[i][j] = __builtin_amdgcn_mfma_f32_16x16x32_bf16(qfl[i][ks], kfh[j], s[i][j], 0, 0, 0);
                }
        }

        // scale, causal mask (only the diagonal tile needs it)
        #pragma unroll
        for (int i = 0; i < 2; ++i)
            #pragma unroll
            for (int j = 0; j < 4; ++j)
                #pragma unroll
                for (int r = 0; r < 4; ++r) s[i][j][r] *= 0.125f;

        if (kt == nt - 1) {
            #pragma unroll
            for (int i = 0; i < 2; ++i) {
                const int rowg = q0 + 16*i + 4*lk;
                #pragma unroll
                for (int j = 0; j < 4; ++j) {
                    const int colg = k0 + 16*j + lr;
                    #pragma unroll
                    for (int r = 0; r < 4; ++r)
                        if (colg > rowg + r) s[i][j][r] = -1e30f;
                }
            }
        }

        // ---- online softmax (row groups = 16 lanes sharing lane>>4) ----
        #pragma unroll
        for (int i = 0; i < 2; ++i)
            #pragma unroll
            for (int r = 0; r < 4; ++r) {
                float mx = fmaxf(fmaxf(s[i][0][r], s[i][1][r]), fmaxf(s[i][2][r], s[i][3][r]));
                #pragma unroll
                for (int off = 1; off < 16; off <<= 1)
                    mx = fmaxf(mx, __shfl_xor(mx, off, 16));
                const float mnew = fmaxf(mrun[i][r], mx);
                const float al   = __expf(mrun[i][r] - mnew);
                float p0 = __expf(s[i][0][r] - mnew);
                float p1 = __expf(s[i][1][r] - mnew);
                float p2 = __expf(s[i][2][r] - mnew);
                float p3 = __expf(s[i][3][r] - mnew);
                float sum = p0 + p1 + p2 + p3;
                #pragma unroll
                for (int off = 1; off < 16; off <<= 1)
                    sum += __shfl_xor(sum, off, 16);
                lrun[i][r] = lrun[i][r] * al + sum;
                mrun[i][r] = mnew;
                #pragma unroll
                for (int n = 0; n < 4; ++n) o[i][n][r] *= al;
                s[i][0][r] = p0; s[i][1][r] = p1; s[i][2][r] = p2; s[i][3][r] = p3;
            }

        // ---- P: C-layout -> LDS -> A-layout (per-wave region, in-order LDS) ----
        #pragma unroll
        for (int i = 0; i < 2; ++i)
            #pragma unroll
            for (int j = 0; j < 4; ++j)
                #pragma unroll
                for (int r = 0; r < 4; ++r)
                    P[(16*i + 4*lk + r)*68 + 16*j + lr] = s[i][j][r];
        asm volatile("s_waitcnt lgkmcnt(0)" ::: "memory");
        __builtin_amdgcn_sched_barrier(0);

        // ---- O += P V (bf16x3) ----
        #pragma unroll
        for (int ks = 0; ks < 2; ++ks) {
            short8 pah[2], pal[2];
            #pragma unroll
            for (int i = 0; i < 2; ++i) {
                const float4 x0 = *(const float4*)&P[(16*i + lr)*68 + 32*ks + 8*lk];
                const float4 x1 = *(const float4*)&P[(16*i + lr)*68 + 32*ks + 8*lk + 4];
                const float xs[8] = {x0.x, x0.y, x0.z, x0.w, x1.x, x1.y, x1.z, x1.w};
                short8 ph, pl;
                #pragma unroll
                for (int e = 0; e < 8; ++e) {
                    const u16 hh = f2bf(xs[e]);
                    ph[e] = (short)hh;
                    pl[e] = (short)f2bf(xs[e] - bf2f(hh));
                }
                pah[i] = ph; pal[i] = pl;
            }
            short8 vfh[4], vfl[4];
            #pragma unroll
            for (int n = 0; n < 4; ++n) {
                const size_t a = ((size_t)bh * DKH + 16*n + lr) * TLEN + k0 + 32*ks + 8*lk;
                vfh[n] = *(const short8*)(Vth + a);
                vfl[n] = *(const short8*)(Vtl + a);
            }
            #pragma unroll
            for (int i = 0; i < 2; ++i)
                #pragma unroll
                for (int n = 0; n < 4; ++n) {
                    o[i][n] = __builtin_amdgcn_mfma_f32_16x16x32_bf16(pah[i], vfh[n], o[i][n], 0, 0, 0);
                    o[i][n] = __builtin_amdgcn_mfma_f32_16x16x32_bf16(pah[i], vfl[n], o[i][n], 0, 0, 0);
                    o[i][n] = __builtin_amdgcn_mfma_f32_16x16x32_bf16(pal[i], vfh[n], o[i][n], 0, 0, 0);
                }
        }
    }

    // ---- epilogue: O/l -> bf16 hi/lo ----
    #pragma unroll
    for (int i = 0; i < 2; ++i)
        #pragma unroll
        for (int r = 0; r < 4; ++r) {
            const float inv = 1.0f / lrun[i][r];
            const size_t row = rbase + q0 + 16*i + 4*lk + r;
            #pragma unroll
            for (int n = 0; n < 4; ++n) {
                const float v = o[i][n][r] * inv;
                const u16 hh = f2bf(v);
                const u16 ll = f2bf(v - bf2f(hh));
                Ahh[row * D_MODEL + hc + 16*n + lr] = hh;
                Ahl[row * D_MODEL + hc + 16*n + lr] = ll;
            }
        }
}

extern "C" void kernel_launch(void* const* d_in, const int* in_sizes, int n_in,
                              void* d_out, int out_size, void* d_ws, size_t ws_size,
                              hipStream_t stream)
{
    const float* x  = (const float*)d_in[0];
    const float* Wq = (const float*)d_in[1];
    const float* Wk = (const float*)d_in[2];
    const float* Wv = (const float*)d_in[3];
    const float* Wo = (const float*)d_in[4];
    float* out = (float*)d_out;

    const size_t MS = (size_t)MTOT * D_MODEL;      // 4M elems
    const size_t WS = (size_t)D_MODEL * D_MODEL;   // 1M elems

    u8* p = (u8*)d_ws;
    float* Qb  = (float*)p;  p += MS * 4;          // 16MB (reused as Ahh/Ahl after Q/K split)
    float* Kb  = (float*)p;  p += MS * 4;          // 16MB
    float* Vb  = (float*)p;  p += MS * 4;          // 16MB
    u16* QKh   = (u16*)p;    p += 2 * MS * 2;      // 16MB (Q then K, contiguous)
    u16* QKl   = (u16*)p;    p += 2 * MS * 2;      // 16MB
    u16* Xhi   = (u16*)p;    p += MS * 2;          // 8MB (reused as Vth after QKV GEMM)
    u16* Xlo   = (u16*)p;    p += MS * 2;          // 8MB (reused as Vtl)
    u16* Wqh = (u16*)p; p += WS*2;  u16* Wql = (u16*)p; p += WS*2;
    u16* Wkh = (u16*)p; p += WS*2;  u16* Wkl = (u16*)p; p += WS*2;
    u16* Wvh = (u16*)p; p += WS*2;  u16* Wvl = (u16*)p; p += WS*2;
    u16* Woh = (u16*)p; p += WS*2;  u16* Wol = (u16*)p; p += WS*2;   // total 112MB
    u16* Vth = Xhi;  u16* Vtl = Xlo;               // alias: x-splits dead after QKV GEMM
    u16* Ahh = (u16*)Qb;  u16* Ahl = Ahh + MS;     // alias: Qb dead after Q/K split

    dim3 blk(256);

    // input splits
    split_bf16x2<<<dim3(MS / 1024), blk, 0, stream>>>(x,  Xhi, Xlo);
    split_bf16x2<<<dim3(WS / 1024), blk, 0, stream>>>(Wq, Wqh, Wql);
    split_bf16x2<<<dim3(WS / 1024), blk, 0, stream>>>(Wk, Wkh, Wkl);
    split_bf16x2<<<dim3(WS / 1024), blk, 0, stream>>>(Wv, Wvh, Wvl);
    split_bf16x2<<<dim3(WS / 1024), blk, 0, stream>>>(Wo, Woh, Wol);

    // QKV projections (bf16x3 MFMA)
    gemm_bf16x3<<<dim3(D_MODEL/128, MTOT/128, 3), blk, 0, stream>>>(
        Xhi, Xlo, Wqh, Wql, Wkh, Wkl, Wvh, Wvl, Qb, Kb, Vb);

    // re-split Q,K (contiguous -> one dispatch); transpose+split V
    split_bf16x2<<<dim3(2 * MS / 1024), blk, 0, stream>>>(Qb, QKh, QKl);
    vsplit_t<<<dim3(TLEN/64, BSZ*NHEADS), blk, 0, stream>>>(Vb, Vth, Vtl);

    // MFMA flash attention -> bf16 hi/lo attention output
    attn_mfma<<<dim3(TLEN/128, BSZ*NHEADS), blk, 0, stream>>>(
        QKh, QKl, QKh + MS, QKl + MS, Vth, Vtl, Ahh, Ahl);

    // output projection
    gemm_bf16x3<<<dim3(D_MODEL/128, MTOT/128, 1), blk, 0, stream>>>(
        Ahh, Ahl, Woh, Wol, Woh, Wol, Woh, Wol, out, out, out);
}

// Round 12
// 422.886 us; speedup vs baseline: 1.3698x; 1.3698x over previous
//
#include <hip/hip_runtime.h>

#define D_MODEL 1024
#define NHEADS  16
#define DKH     64
#define BSZ     2
#define TLEN    2048
#define MTOT    (BSZ*TLEN)   // 4096

typedef unsigned short u16;
typedef unsigned int   u32;
typedef unsigned char  u8;
typedef __attribute__((ext_vector_type(8))) short short8;
typedef __attribute__((ext_vector_type(4))) float floatx4;

// ---------------- fp32 -> (bf16 hi, bf16 lo) split helpers ----------------
__device__ __forceinline__ u16 f2bf(float x) {
    u32 u = __float_as_uint(x);
    u += 0x7FFFu + ((u >> 16) & 1u);   // RNE
    return (u16)(u >> 16);
}
__device__ __forceinline__ float bf2f(u16 h) { return __uint_as_float(((u32)h) << 16); }

__device__ __forceinline__ void split_body(const float* __restrict__ in,
                                           u16* __restrict__ hi, u16* __restrict__ lo,
                                           int idx)
{
    float4 v = *(const float4*)&in[idx];
    u16 h0 = f2bf(v.x), h1 = f2bf(v.y), h2 = f2bf(v.z), h3 = f2bf(v.w);
    u16 l0 = f2bf(v.x - bf2f(h0));
    u16 l1 = f2bf(v.y - bf2f(h1));
    u16 l2 = f2bf(v.z - bf2f(h2));
    u16 l3 = f2bf(v.w - bf2f(h3));
    uint2 hv, lv;
    hv.x = (u32)h0 | ((u32)h1 << 16);  hv.y = (u32)h2 | ((u32)h3 << 16);
    lv.x = (u32)l0 | ((u32)l1 << 16);  lv.y = (u32)l2 | ((u32)l3 << 16);
    *(uint2*)&hi[idx] = hv;
    *(uint2*)&lo[idx] = lv;
}

__global__ __launch_bounds__(256) void split_bf16x2(
    const float* __restrict__ in, u16* __restrict__ hi, u16* __restrict__ lo)
{
    split_body(in, hi, lo, (blockIdx.x * 256 + threadIdx.x) * 4);
}

// fused 4-weight split (grid.y selects the matrix)
__global__ __launch_bounds__(256) void split_w4(
    const float* __restrict__ W0, const float* __restrict__ W1,
    const float* __restrict__ W2, const float* __restrict__ W3,
    u16* __restrict__ h0, u16* __restrict__ l0, u16* __restrict__ h1, u16* __restrict__ l1,
    u16* __restrict__ h2, u16* __restrict__ l2, u16* __restrict__ h3, u16* __restrict__ l3)
{
    const int z = blockIdx.y;
    const float* in = (z == 0) ? W0 : (z == 1) ? W1 : (z == 2) ? W2 : W3;
    u16* hi = (z == 0) ? h0 : (z == 1) ? h1 : (z == 2) ? h2 : h3;
    u16* lo = (z == 0) ? l0 : (z == 1) ? l1 : (z == 2) ? l2 : l3;
    split_body(in, hi, lo, (blockIdx.x * 256 + threadIdx.x) * 4);
}

// ---------------- V transpose + split: Vb[4096][1024] fp32 -> Vt[bh][64 d][2048 t] bf16 hi/lo ----------------
__global__ __launch_bounds__(256) void vsplit_t(
    const float* __restrict__ V, u16* __restrict__ Vth, u16* __restrict__ Vtl)
{
    __shared__ float Vs[64][68];
    const int tid = threadIdx.x;
    const int t0  = blockIdx.x * 64;
    const int bh  = blockIdx.y;
    const int b   = bh >> 4, h = bh & 15;
    const size_t inbase = ((size_t)b * TLEN + t0) * D_MODEL + h * DKH;

    #pragma unroll
    for (int it = 0; it < 4; ++it) {
        int i = tid + it * 256;
        int r = i >> 4, cq = i & 15;
        *(float4*)&Vs[r][4*cq] = *(const float4*)&V[inbase + (size_t)r * D_MODEL + 4*cq];
    }
    __syncthreads();

    const size_t outbase = (size_t)bh * DKH * TLEN + t0;
    #pragma unroll
    for (int it = 0; it < 4; ++it) {
        int i = tid + it * 256;
        int d = i >> 4, ck = i & 15;
        int tk = 4 * ck;
        float v0 = Vs[tk+0][d], v1 = Vs[tk+1][d], v2 = Vs[tk+2][d], v3 = Vs[tk+3][d];
        u16 h0 = f2bf(v0), h1 = f2bf(v1), h2 = f2bf(v2), h3 = f2bf(v3);
        u16 l0 = f2bf(v0 - bf2f(h0));
        u16 l1 = f2bf(v1 - bf2f(h1));
        u16 l2 = f2bf(v2 - bf2f(h2));
        u16 l3 = f2bf(v3 - bf2f(h3));
        uint2 hv, lv;
        hv.x = (u32)h0 | ((u32)h1 << 16);  hv.y = (u32)h2 | ((u32)h3 << 16);
        lv.x = (u32)l0 | ((u32)l1 << 16);  lv.y = (u32)l2 | ((u32)l3 << 16);
        *(uint2*)&Vth[outbase + (size_t)d * TLEN + tk] = hv;
        *(uint2*)&Vtl[outbase + (size_t)d * TLEN + tk] = lv;
    }
}

// ---------------- bf16x3 MFMA GEMM (round-3-PASSED reg-staging body) ----------------
// C[m][n] = sum_k A[m][k]*W[n][k], K=N=1024.  128x128 tile, BK=32, 4 waves (2x2),
// each wave 64x64 = 4x4 frags of 16x16x32.  LDS fragment-major: frag s chunk l (16B)
// = row s*16+(l&15), k=(l>>4)*8..+7.
// Epilogue modes (per z): 0 = fp32 -> o1;  1 = bf16 hi/lo -> (o1,o2);  2 = same, scaled 0.125.
__global__ __launch_bounds__(256) void gemm_bf16x3(
    const u16* __restrict__ Ahi, const u16* __restrict__ Alo,
    const u16* __restrict__ B0h, const u16* __restrict__ B0l,
    const u16* __restrict__ B1h, const u16* __restrict__ B1l,
    const u16* __restrict__ B2h, const u16* __restrict__ B2l,
    void* __restrict__ o1z0, void* __restrict__ o2z0,
    void* __restrict__ o1z1, void* __restrict__ o2z1,
    void* __restrict__ o1z2, void* __restrict__ o2z2,
    int m0_, int m1_, int m2_)
{
    const u16* __restrict__ Bh = (blockIdx.z == 0) ? B0h : ((blockIdx.z == 1) ? B1h : B2h);
    const u16* __restrict__ Bl = (blockIdx.z == 0) ? B0l : ((blockIdx.z == 1) ? B1l : B2l);
    void* o1 = (blockIdx.z == 0) ? o1z0 : ((blockIdx.z == 1) ? o1z1 : o1z2);
    void* o2 = (blockIdx.z == 0) ? o2z0 : ((blockIdx.z == 1) ? o2z1 : o2z2);
    const int mode = (blockIdx.z == 0) ? m0_ : ((blockIdx.z == 1) ? m1_ : m2_);

    __shared__ __align__(16) short lds[4][4096];   // Ahi, Alo, Bhi, Blo tiles

    const int tid  = threadIdx.x;
    const int lane = tid & 63;
    const int w    = tid >> 6;
    const int wr   = w >> 1;
    const int wc   = w & 1;
    const int m0   = blockIdx.y * 128;
    const int n0   = blockIdx.x * 128;
    const int lr   = lane & 15;
    const int lkq  = lane >> 4;

    const size_t offA0 = (size_t)(m0 + (w*2 + 0)*16 + lr) * D_MODEL + lkq*8;
    const size_t offA1 = (size_t)(m0 + (w*2 + 1)*16 + lr) * D_MODEL + lkq*8;
    const size_t offB0 = (size_t)(n0 + (w*2 + 0)*16 + lr) * D_MODEL + lkq*8;
    const size_t offB1 = (size_t)(n0 + (w*2 + 1)*16 + lr) * D_MODEL + lkq*8;

    floatx4 acc[4][4];
    #pragma unroll
    for (int i = 0; i < 4; ++i)
        #pragma unroll
        for (int j = 0; j < 4; ++j) acc[i][j] = (floatx4){0.f, 0.f, 0.f, 0.f};

    short8 sA0h, sA1h, sA0l, sA1l, sB0h, sB1h, sB0l, sB1l;
    sA0h = *(const short8*)(Ahi + offA0);  sA1h = *(const short8*)(Ahi + offA1);
    sA0l = *(const short8*)(Alo + offA0);  sA1l = *(const short8*)(Alo + offA1);
    sB0h = *(const short8*)(Bh  + offB0);  sB1h = *(const short8*)(Bh  + offB1);
    sB0l = *(const short8*)(Bl  + offB0);  sB1l = *(const short8*)(Bl  + offB1);

    const int c0 = (w*128 + 0*64 + lane) * 8;
    const int c1 = (w*128 + 1*64 + lane) * 8;

    for (int ks = 0; ks < D_MODEL/32; ++ks) {
        *(short8*)&lds[0][c0] = sA0h;  *(short8*)&lds[0][c1] = sA1h;
        *(short8*)&lds[1][c0] = sA0l;  *(short8*)&lds[1][c1] = sA1l;
        *(short8*)&lds[2][c0] = sB0h;  *(short8*)&lds[2][c1] = sB1h;
        *(short8*)&lds[3][c0] = sB0l;  *(short8*)&lds[3][c1] = sB1l;
        __syncthreads();

        if (ks + 1 < D_MODEL/32) {
            const size_t kb = (size_t)(ks + 1) * 32;
            sA0h = *(const short8*)(Ahi + offA0 + kb);  sA1h = *(const short8*)(Ahi + offA1 + kb);
            sA0l = *(const short8*)(Alo + offA0 + kb);  sA1l = *(const short8*)(Alo + offA1 + kb);
            sB0h = *(const short8*)(Bh  + offB0 + kb);  sB1h = *(const short8*)(Bh  + offB1 + kb);
            sB0l = *(const short8*)(Bl  + offB0 + kb);  sB1l = *(const short8*)(Bl  + offB1 + kb);
        }

        short8 ah[4], al[4], bh[4], bl[4];
        #pragma unroll
        for (int i = 0; i < 4; ++i) {
            const int ci = ((wr*4 + i)*64 + lane) * 8;
            ah[i] = *(const short8*)&lds[0][ci];
            al[i] = *(const short8*)&lds[1][ci];
        }
        #pragma unroll
        for (int j = 0; j < 4; ++j) {
            const int cj = ((wc*4 + j)*64 + lane) * 8;
            bh[j] = *(const short8*)&lds[2][cj];
            bl[j] = *(const short8*)&lds[3][cj];
        }

        #pragma unroll
        for (int i = 0; i < 4; ++i)
            #pragma unroll
            for (int j = 0; j < 4; ++j) {
                acc[i][j] = __builtin_amdgcn_mfma_f32_16x16x32_bf16(ah[i], bh[j], acc[i][j], 0, 0, 0);
                acc[i][j] = __builtin_amdgcn_mfma_f32_16x16x32_bf16(ah[i], bl[j], acc[i][j], 0, 0, 0);
                acc[i][j] = __builtin_amdgcn_mfma_f32_16x16x32_bf16(al[i], bh[j], acc[i][j], 0, 0, 0);
            }
        __syncthreads();
    }

    // C/D layout: col = lane&15, row = (lane>>4)*4 + reg
    if (mode == 0) {
        float* __restrict__ C = (float*)o1;
        #pragma unroll
        for (int i = 0; i < 4; ++i) {
            const int row0 = m0 + wr*64 + i*16 + (lane >> 4)*4;
            #pragma unroll
            for (int j = 0; j < 4; ++j) {
                const int col = n0 + wc*64 + j*16 + (lane & 15);
                #pragma unroll
                for (int r = 0; r < 4; ++r)
                    C[(size_t)(row0 + r) * D_MODEL + col] = acc[i][j][r];
            }
        }
    } else {
        const float sc = (mode == 2) ? 0.125f : 1.0f;
        u16* __restrict__ H = (u16*)o1;
        u16* __restrict__ L = (u16*)o2;
        #pragma unroll
        for (int i = 0; i < 4; ++i) {
            const int row0 = m0 + wr*64 + i*16 + (lane >> 4)*4;
            #pragma unroll
            for (int j = 0; j < 4; ++j) {
                const int col = n0 + wc*64 + j*16 + (lane & 15);
                #pragma unroll
                for (int r = 0; r < 4; ++r) {
                    const float v = acc[i][j][r] * sc;
                    const u16 hh = f2bf(v);
                    H[(size_t)(row0 + r) * D_MODEL + col] = hh;
                    L[(size_t)(row0 + r) * D_MODEL + col] = f2bf(v - bf2f(hh));
                }
            }
        }
    }
}

// ---------------- MFMA flash attention v5 (swapped QK^T, block-shared K/V via reg->ds_write), causal ----------------
// Block = 64 q-rows (4 waves x 16).  s = mfma(K,Q) -> S col=q=lq, row=k; softmax state
// (mrun/lrun/alpha) is per-lane for q-row lq.  The PV accumulator o[n] is C/D layout:
// reg r = q-row 4g+r, col lq -> the per-tile O-rescale must use q-row (4g+r)'s alpha,
// fetched via __shfl(alpha, 4g+r).  (Round-5/8 bug: used lane-local alpha.)
__global__ __launch_bounds__(256) void attn_mfma(
    const u16* __restrict__ Qh, const u16* __restrict__ Ql,
    const u16* __restrict__ Kh, const u16* __restrict__ Kl,
    const u16* __restrict__ Vth, const u16* __restrict__ Vtl,
    u16* __restrict__ Ahh, u16* __restrict__ Ahl)
{
    __shared__ __align__(16) short KhL[4096], KlL[4096], VhL[4096], VlL[4096];  // 8KB each
    __shared__ __align__(16) float Plds[4][16*68];

    const int tid  = threadIdx.x;
    const int lane = tid & 63;
    const int w    = tid >> 6;
    const int bh   = blockIdx.y;
    const int b    = bh >> 4;
    const int q0   = blockIdx.x * 64 + w * 16;   // this wave's 16 q-rows
    const size_t rbase = (size_t)b * TLEN;
    const int hc   = (bh & 15) * DKH;
    const int lq   = lane & 15;
    const int g    = lane >> 4;

    float* P = Plds[w];

    // Q frags (B-operand: col = lq = q, k = 32ks + 8g..+7)
    short8 qfh[2], qfl[2];
    #pragma unroll
    for (int ks = 0; ks < 2; ++ks) {
        const size_t a = (rbase + q0 + lq) * D_MODEL + hc + 32*ks + 8*g;
        qfh[ks] = *(const short8*)(Qh + a);
        qfl[ks] = *(const short8*)(Ql + a);
    }

    // staging sources: this wave stages K frag j=w and V frag n=w (both ks, hi+lo)
    const size_t ksrc = (rbase + 16*w + lq) * D_MODEL + hc + 8*g;    // + k0*D_MODEL (+32 for ks=1)
    const size_t vsrc = ((size_t)bh * DKH + 16*w + lq) * TLEN + 8*g; // + k0 (+32 for ks=1)

    // LDS write chunk indices for this wave's frags (frag f chunk lane at (f*64+lane)*8 shorts)
    const int wc0 = ((w*2 + 0)*64 + lane) * 8;
    const int wc1 = ((w*2 + 1)*64 + lane) * 8;

    floatx4 o[4];
    #pragma unroll
    for (int n = 0; n < 4; ++n) o[n] = (floatx4){0.f, 0.f, 0.f, 0.f};
    float mrun = -1e30f, lrun = 0.f;

    const int nt = blockIdx.x + 1;
    for (int kt = 0; kt < nt; ++kt) {
        const int k0 = kt * 64;

        // ---- stage loads to regs (issued before barrier; latency overlaps) ----
        const u16* kp = Kh  + ksrc + (size_t)k0 * D_MODEL;
        const u16* lp = Kl  + ksrc + (size_t)k0 * D_MODEL;
        const u16* vp = Vth + vsrc + k0;
        const u16* up = Vtl + vsrc + k0;
        short8 rkh0 = *(const short8*)(kp);
        short8 rkh1 = *(const short8*)(kp + 32);
        short8 rkl0 = *(const short8*)(lp);
        short8 rkl1 = *(const short8*)(lp + 32);
        short8 rvh0 = *(const short8*)(vp);
        short8 rvh1 = *(const short8*)(vp + 32);
        short8 rvl0 = *(const short8*)(up);
        short8 rvl1 = *(const short8*)(up + 32);

        __syncthreads();   // prev tile's readers done before overwrite
        *(short8*)&KhL[wc0] = rkh0;  *(short8*)&KhL[wc1] = rkh1;
        *(short8*)&KlL[wc0] = rkl0;  *(short8*)&KlL[wc1] = rkl1;
        *(short8*)&VhL[wc0] = rvh0;  *(short8*)&VhL[wc1] = rvh1;
        *(short8*)&VlL[wc0] = rvl0;  *(short8*)&VlL[wc1] = rvl1;
        __syncthreads();   // staging visible to all waves

        // ---- S = K Q (swapped): s[j] rows k = k0+16j+4g+r, col q = q0+lq ----
        floatx4 s[4];
        #pragma unroll
        for (int j = 0; j < 4; ++j) s[j] = (floatx4){0.f, 0.f, 0.f, 0.f};
        #pragma unroll
        for (int ks = 0; ks < 2; ++ks)
            #pragma unroll
            for (int j = 0; j < 4; ++j) {
                const short8 kh = *(const short8*)&KhL[((j*2 + ks)*64 + lane)*8];
                const short8 kl = *(const short8*)&KlL[((j*2 + ks)*64 + lane)*8];
                s[j] = __builtin_amdgcn_mfma_f32_16x16x32_bf16(kh, qfh[ks], s[j], 0, 0, 0);
                s[j] = __builtin_amdgcn_mfma_f32_16x16x32_bf16(kh, qfl[ks], s[j], 0, 0, 0);
                s[j] = __builtin_amdgcn_mfma_f32_16x16x32_bf16(kl, qfh[ks], s[j], 0, 0, 0);
            }

        // ---- causal mask on diagonal tile ----
        if (kt == nt - 1) {
            const int qg = q0 + lq;
            #pragma unroll
            for (int j = 0; j < 4; ++j)
                #pragma unroll
                for (int r = 0; r < 4; ++r)
                    if (k0 + 16*j + 4*g + r > qg) s[j][r] = -1e30f;
        }

        // ---- softmax (state owned per-lane for q-row lq): reg tree + 2 shfl_xor ----
        float mx = s[0][0];
        #pragma unroll
        for (int j = 0; j < 4; ++j)
            #pragma unroll
            for (int r = 0; r < 4; ++r) mx = fmaxf(mx, s[j][r]);
        mx = fmaxf(mx, __shfl_xor(mx, 16));
        mx = fmaxf(mx, __shfl_xor(mx, 32));
        const float mnew  = fmaxf(mrun, mx);
        const float alpha = __expf(mrun - mnew);
        float sum = 0.f;
        #pragma unroll
        for (int j = 0; j < 4; ++j)
            #pragma unroll
            for (int r = 0; r < 4; ++r) {
                s[j][r] = __expf(s[j][r] - mnew);
                sum += s[j][r];
            }
        sum += __shfl_xor(sum, 16);
        sum += __shfl_xor(sum, 32);
        lrun = lrun * alpha + sum;
        mrun = mnew;

        // ---- O-rescale: o[n][r] belongs to q-row (q0+4g+r) -> use THAT row's alpha ----
        #pragma unroll
        for (int r = 0; r < 4; ++r) {
            const float a_r = __shfl(alpha, 4*g + r);
            #pragma unroll
            for (int n = 0; n < 4; ++n) o[n][r] *= a_r;
        }

        // ---- P transpose via per-wave LDS: write [q=lq][k=16j+4g..+3] ----
        #pragma unroll
        for (int j = 0; j < 4; ++j)
            *(float4*)&P[lq*68 + 16*j + 4*g] = make_float4(s[j][0], s[j][1], s[j][2], s[j][3]);
        asm volatile("s_waitcnt lgkmcnt(0)" ::: "memory");
        __builtin_amdgcn_sched_barrier(0);

        // ---- P read back as A-frag (row=lq, k=32ks+8g..+7) + hi/lo split ----
        short8 pah[2], pal[2];
        #pragma unroll
        for (int ks = 0; ks < 2; ++ks) {
            const float4 x0 = *(const float4*)&P[lq*68 + 32*ks + 8*g];
            const float4 x1 = *(const float4*)&P[lq*68 + 32*ks + 8*g + 4];
            const float xs[8] = {x0.x, x0.y, x0.z, x0.w, x1.x, x1.y, x1.z, x1.w};
            short8 ph, pl;
            #pragma unroll
            for (int e = 0; e < 8; ++e) {
                const u16 hh = f2bf(xs[e]);
                ph[e] = (short)hh;
                pl[e] = (short)f2bf(xs[e] - bf2f(hh));
            }
            pah[ks] = ph; pal[ks] = pl;
        }

        // ---- O += P V from shared LDS ----
        #pragma unroll
        for (int ks = 0; ks < 2; ++ks)
            #pragma unroll
            for (int n = 0; n < 4; ++n) {
                const short8 vh = *(const short8*)&VhL[((n*2 + ks)*64 + lane)*8];
                const short8 vl = *(const short8*)&VlL[((n*2 + ks)*64 + lane)*8];
                o[n] = __builtin_amdgcn_mfma_f32_16x16x32_bf16(pah[ks], vh, o[n], 0, 0, 0);
                o[n] = __builtin_amdgcn_mfma_f32_16x16x32_bf16(pah[ks], vl, o[n], 0, 0, 0);
                o[n] = __builtin_amdgcn_mfma_f32_16x16x32_bf16(pal[ks], vh, o[n], 0, 0, 0);
            }
    }

    // ---- epilogue: rows q = q0 + 4g + r; that row's l lives in lane (4g+r) ----
    #pragma unroll
    for (int r = 0; r < 4; ++r) {
        const float lr_ = __shfl(lrun, 4*g + r);
        const float inv = 1.0f / lr_;
        const size_t row = rbase + q0 + 4*g + r;
        #pragma unroll
        for (int n = 0; n < 4; ++n) {
            const float v = o[n][r] * inv;
            const u16 hh = f2bf(v);
            Ahh[row * D_MODEL + hc + 16*n + lq] = hh;
            Ahl[row * D_MODEL + hc + 16*n + lq] = f2bf(v - bf2f(hh));
        }
    }
}

extern "C" void kernel_launch(void* const* d_in, const int* in_sizes, int n_in,
                              void* d_out, int out_size, void* d_ws, size_t ws_size,
                              hipStream_t stream)
{
    const float* x  = (const float*)d_in[0];
    const float* Wq = (const float*)d_in[1];
    const float* Wk = (const float*)d_in[2];
    const float* Wv = (const float*)d_in[3];
    const float* Wo = (const float*)d_in[4];
    float* out = (float*)d_out;

    const size_t MS = (size_t)MTOT * D_MODEL;      // 4M elems
    const size_t WS = (size_t)D_MODEL * D_MODEL;   // 1M elems

    u8* p = (u8*)d_ws;
    u16* Qbh = (u16*)p;  p += MS * 2;   // 8MB  (Q hi, pre-scaled 0.125)
    u16* Qbl = (u16*)p;  p += MS * 2;   // 8MB
    u16* Kbh = (u16*)p;  p += MS * 2;   // 8MB
    u16* Kbl = (u16*)p;  p += MS * 2;   // 8MB
    float* Vb = (float*)p; p += MS * 4; // 16MB
    u16* Vth = (u16*)p;  p += MS * 2;   // 8MB
    u16* Vtl = (u16*)p;  p += MS * 2;   // 8MB
    u16* Xhi = (u16*)p;  p += MS * 2;   // 8MB (aliased: Ahh after QKV GEMM)
    u16* Xlo = (u16*)p;  p += MS * 2;   // 8MB (aliased: Ahl)
    u16* Wqh = (u16*)p; p += WS*2;  u16* Wql = (u16*)p; p += WS*2;
    u16* Wkh = (u16*)p; p += WS*2;  u16* Wkl = (u16*)p; p += WS*2;
    u16* Wvh = (u16*)p; p += WS*2;  u16* Wvl = (u16*)p; p += WS*2;
    u16* Woh = (u16*)p; p += WS*2;  u16* Wol = (u16*)p; p += WS*2;   // total 96MB
    u16* Ahh = Xhi;  u16* Ahl = Xlo;    // x-splits dead after QKV GEMM

    dim3 blk(256);

    // input splits (x; 4 weights fused into one dispatch)
    split_bf16x2<<<dim3(MS / 1024), blk, 0, stream>>>(x, Xhi, Xlo);
    split_w4<<<dim3(WS / 1024, 4), blk, 0, stream>>>(
        Wq, Wk, Wv, Wo, Wqh, Wql, Wkh, Wkl, Wvh, Wvl, Woh, Wol);

    // QKV projections; epilogue emits Q (hi/lo, x0.125), K (hi/lo), V (fp32)
    gemm_bf16x3<<<dim3(D_MODEL/128, MTOT/128, 3), blk, 0, stream>>>(
        Xhi, Xlo, Wqh, Wql, Wkh, Wkl, Wvh, Wvl,
        Qbh, Qbl, Kbh, Kbl, Vb, nullptr, 2, 1, 0);

    // transpose+split V
    vsplit_t<<<dim3(TLEN/64, BSZ*NHEADS), blk, 0, stream>>>(Vb, Vth, Vtl);

    // MFMA flash attention (block-shared K/V via reg->ds_write) -> bf16 hi/lo output
    attn_mfma<<<dim3(TLEN/64, BSZ*NHEADS), blk, 0, stream>>>(
        Qbh, Qbl, Kbh, Kbl, Vth, Vtl, Ahh, Ahl);

    // output projection (fp32 out)
    gemm_bf16x3<<<dim3(D_MODEL/128, MTOT/128, 1), blk, 0, stream>>>(
        Ahh, Ahl, Woh, Wol, Woh, Wol, Woh, Wol,
        out, nullptr, out, nullptr, out, nullptr, 0, 0, 0);
}